// Round 1
// baseline (302.913 us; speedup 1.0000x reference)
//
#include <hip/hip_runtime.h>

#define N_THRESH 100
#define NBINS 101   // cnt in [0, 100]

// ---------------------------------------------------------------------------
// Kernel 0: zero the workspace histogram (d_ws is poisoned 0xAA every call).
// ---------------------------------------------------------------------------
__global__ void zero_ws_kernel(unsigned long long* __restrict__ ws) {
    int i = threadIdx.x;
    if (i < NBINS) ws[i] = 0ull;
}

// ---------------------------------------------------------------------------
// Kernel 1: single-pass histogram.
// For each pixel: cnt = #{k in [0,100): t_k < pred}, t_k = float32(double(k)*0.01)
// (bit-exact match of np.arange(0,1,0.01).astype(float32)).
// Packed u64 accumulator: high 32 = gt-positive count, low 32 = total count.
// Per-wave LDS histograms -> one global u64 atomic per bin per block.
// ---------------------------------------------------------------------------
__global__ __launch_bounds__(256) void hist_kernel(
        const float* __restrict__ pred,
        const int* __restrict__ gt,
        unsigned long long* __restrict__ ws,
        int n) {
    __shared__ unsigned long long hist[4][NBINS];
    __shared__ float thr[NBINS + 1];   // thr[100] = sentinel > any pred

    const int tid  = threadIdx.x;
    const int wave = tid >> 6;

    // zero per-wave histograms
    for (int i = tid; i < 4 * NBINS; i += blockDim.x)
        (&hist[0][0])[i] = 0ull;
    // exact threshold table
    if (tid <= N_THRESH)
        thr[tid] = (tid == N_THRESH) ? 2.0f : (float)((double)tid * 0.01);
    __syncthreads();

    const int nvec = n >> 2;
    const float4* __restrict__ p4 = (const float4*)pred;
    const int4*   __restrict__ g4 = (const int4*)gt;
    const int stride = gridDim.x * blockDim.x;

    for (int i = blockIdx.x * blockDim.x + tid; i < nvec; i += stride) {
        float4 p = p4[i];
        int4   g = g4[i];
        float pv[4] = {p.x, p.y, p.z, p.w};
        int   gv[4] = {g.x, g.y, g.z, g.w};
#pragma unroll
        for (int j = 0; j < 4; ++j) {
            float v = pv[j];
            // estimate-then-correct searchsorted(thresholds, v, side='left')
            int c = (int)(v * 100.0f) + 1;
            c = c < 0 ? 0 : (c > N_THRESH ? N_THRESH : c);
            while (c > 0 && thr[c - 1] >= v) --c;
            while (thr[c] < v) ++c;           // thr[100]=2.0 sentinel bounds it
            unsigned long long add =
                ((unsigned long long)(gv[j] != 0) << 32) | 1ull;
            atomicAdd(&hist[wave][c], add);
        }
    }

    // tail (n not multiple of 4) — handled by one thread, empty for N=2^25
    if (blockIdx.x == 0 && tid == 0) {
        for (int i = nvec << 2; i < n; ++i) {
            float v = pred[i];
            int c = (int)(v * 100.0f) + 1;
            c = c < 0 ? 0 : (c > N_THRESH ? N_THRESH : c);
            while (c > 0 && thr[c - 1] >= v) --c;
            while (thr[c] < v) ++c;
            unsigned long long add =
                ((unsigned long long)(gt[i] != 0) << 32) | 1ull;
            atomicAdd(&hist[0][c], add);
        }
    }

    __syncthreads();
    if (tid < NBINS) {
        unsigned long long s = hist[0][tid] + hist[1][tid]
                             + hist[2][tid] + hist[3][tid];
        if (s) atomicAdd(&ws[tid], s);
    }
}

// ---------------------------------------------------------------------------
// Kernel 2: suffix sums + IoU. One block, trivial cost.
// out[0:100] = thresholds, out[100:200] = ious.
// ---------------------------------------------------------------------------
__global__ void finalize_kernel(const unsigned long long* __restrict__ ws,
                                float* __restrict__ out) {
    __shared__ unsigned int pos[NBINS], all[NBINS];
    int k = threadIdx.x;
    if (k < NBINS) {
        unsigned long long h = ws[k];
        pos[k] = (unsigned int)(h >> 32);
        all[k] = (unsigned int)(h & 0xffffffffull);
    }
    __syncthreads();
    if (k < N_THRESH) {
        out[k] = (float)((double)k * 0.01);
        unsigned long long tp = 0, pp = 0, ngt = 0;
        for (int c = k + 1; c <= N_THRESH; ++c) { tp += pos[c]; pp += all[c]; }
        for (int c = 0; c <= N_THRESH; ++c) ngt += pos[c];
        long long uni = (long long)(pp + ngt - tp);   // TP + FP + FN
        double iou = (uni > 0) ? (double)tp / (double)uni : 0.0;
        out[N_THRESH + k] = (float)iou;
    }
}

// ---------------------------------------------------------------------------
extern "C" void kernel_launch(void* const* d_in, const int* in_sizes, int n_in,
                              void* d_out, int out_size, void* d_ws, size_t ws_size,
                              hipStream_t stream) {
    const float* pred = (const float*)d_in[0];
    const int*   gt   = (const int*)d_in[1];
    float* out = (float*)d_out;
    unsigned long long* ws = (unsigned long long*)d_ws;
    int n = in_sizes[0];

    zero_ws_kernel<<<1, 128, 0, stream>>>(ws);
    // 2048 blocks x 256 threads = 8 blocks/CU on 256 CUs (fully resident)
    hist_kernel<<<2048, 256, 0, stream>>>(pred, gt, ws, n);
    finalize_kernel<<<1, 128, 0, stream>>>(ws, out);
}

// Round 2
// 284.821 us; speedup vs baseline: 1.0635x; 1.0635x over previous
//
#include <hip/hip_runtime.h>

#define N_THRESH 100
#define NBINS 101   // cnt in [0, 100]
#define NSUB 8      // sub-histograms per block (2 per wave, lane-parity split)

// ---------------------------------------------------------------------------
// Kernel 0: zero the workspace histogram (d_ws is poisoned 0xAA every call).
// ---------------------------------------------------------------------------
__global__ void zero_ws_kernel(unsigned long long* __restrict__ ws) {
    int i = threadIdx.x;
    if (i < NBINS) ws[i] = 0ull;
}

// ---------------------------------------------------------------------------
// Branch-free exact bin: cnt = searchsorted(thresholds, v, side='left'),
// thresholds[k] = float32(double(k)*0.01)  (bit-exact np.arange match).
// e = trunc(fl(v*100)) is within 1 of the answer (error analysis:
// |fl(v*100)-100v| <= 6e-6, |t_k - k/100| <= 6e-8), so
// cnt = e + (t_e < v) + (t_{e+1} < v) exactly. All in registers, no LDS.
// ---------------------------------------------------------------------------
__device__ __forceinline__ int bin_of(float v) {
    int e = (int)(v * 100.0f);
    e = e < 0 ? 0 : (e > 99 ? 99 : e);
    double ed = (double)e * 0.01;
    float t0 = (float)ed;           // threshold e
    float t1 = (float)(ed + 0.01);  // threshold e+1 (==1.0f when e==99: always >= v)
    int c = e + (t0 < v ? 1 : 0) + (t1 < v ? 1 : 0);
    return c > N_THRESH ? N_THRESH : c;
}

__device__ __forceinline__ void accum4(unsigned long long* __restrict__ h,
                                       float4 p, int4 g) {
    int c0 = bin_of(p.x), c1 = bin_of(p.y), c2 = bin_of(p.z), c3 = bin_of(p.w);
    atomicAdd(&h[c0], ((unsigned long long)(g.x != 0) << 32) | 1ull);
    atomicAdd(&h[c1], ((unsigned long long)(g.y != 0) << 32) | 1ull);
    atomicAdd(&h[c2], ((unsigned long long)(g.z != 0) << 32) | 1ull);
    atomicAdd(&h[c3], ((unsigned long long)(g.w != 0) << 32) | 1ull);
}

// ---------------------------------------------------------------------------
// Kernel 1: single-pass histogram. Packed u64: high32 = gt-positive, low32 =
// total. 8 LDS sub-histograms -> one global u64 atomic per bin per block.
// ---------------------------------------------------------------------------
__global__ __launch_bounds__(256) void hist_kernel(
        const float* __restrict__ pred,
        const int* __restrict__ gt,
        unsigned long long* __restrict__ ws,
        int n) {
    __shared__ unsigned long long hist[NSUB][NBINS];

    const int tid = threadIdx.x;
    // 2 sub-histograms per wave, chosen by lane parity
    const int sub = ((tid >> 6) << 1) | (tid & 1);
    unsigned long long* __restrict__ h = hist[sub];

    for (int i = tid; i < NSUB * NBINS; i += blockDim.x)
        (&hist[0][0])[i] = 0ull;
    __syncthreads();

    const int nvec = n >> 2;
    const float4* __restrict__ p4 = (const float4*)pred;
    const int4*   __restrict__ g4 = (const int4*)gt;
    const int gsz = gridDim.x * blockDim.x;

    int i = blockIdx.x * blockDim.x + tid;
    // 2x unrolled: both load pairs issued before any dependent compute
    for (; i + gsz < nvec; i += 2 * gsz) {
        float4 pa = p4[i];
        int4   ga = g4[i];
        float4 pb = p4[i + gsz];
        int4   gb = g4[i + gsz];
        accum4(h, pa, ga);
        accum4(h, pb, gb);
    }
    for (; i < nvec; i += gsz) {
        accum4(h, p4[i], g4[i]);
    }

    // tail (n not multiple of 4) — empty for N=2^25
    if (blockIdx.x == 0 && tid == 0) {
        for (int k = nvec << 2; k < n; ++k) {
            int c = bin_of(pred[k]);
            atomicAdd(&hist[0][c],
                      ((unsigned long long)(gt[k] != 0) << 32) | 1ull);
        }
    }

    __syncthreads();
    if (tid < NBINS) {
        unsigned long long s = 0ull;
#pragma unroll
        for (int w = 0; w < NSUB; ++w) s += hist[w][tid];
        if (s) atomicAdd(&ws[tid], s);
    }
}

// ---------------------------------------------------------------------------
// Kernel 2: suffix sums + IoU. One block, trivial cost.
// out[0:100] = thresholds, out[100:200] = ious.
// ---------------------------------------------------------------------------
__global__ void finalize_kernel(const unsigned long long* __restrict__ ws,
                                float* __restrict__ out) {
    __shared__ unsigned int pos[NBINS], all[NBINS];
    int k = threadIdx.x;
    if (k < NBINS) {
        unsigned long long h = ws[k];
        pos[k] = (unsigned int)(h >> 32);
        all[k] = (unsigned int)(h & 0xffffffffull);
    }
    __syncthreads();
    if (k < N_THRESH) {
        out[k] = (float)((double)k * 0.01);
        unsigned long long tp = 0, pp = 0, ngt = 0;
        for (int c = k + 1; c <= N_THRESH; ++c) { tp += pos[c]; pp += all[c]; }
        for (int c = 0; c <= N_THRESH; ++c) ngt += pos[c];
        long long uni = (long long)(pp + ngt - tp);   // TP + FP + FN
        double iou = (uni > 0) ? (double)tp / (double)uni : 0.0;
        out[N_THRESH + k] = (float)iou;
    }
}

// ---------------------------------------------------------------------------
extern "C" void kernel_launch(void* const* d_in, const int* in_sizes, int n_in,
                              void* d_out, int out_size, void* d_ws, size_t ws_size,
                              hipStream_t stream) {
    const float* pred = (const float*)d_in[0];
    const int*   gt   = (const int*)d_in[1];
    float* out = (float*)d_out;
    unsigned long long* ws = (unsigned long long*)d_ws;
    int n = in_sizes[0];

    zero_ws_kernel<<<1, 128, 0, stream>>>(ws);
    // 2048 blocks x 256 threads = 8 blocks/CU on 256 CUs (fully resident)
    hist_kernel<<<2048, 256, 0, stream>>>(pred, gt, ws, n);
    finalize_kernel<<<1, 128, 0, stream>>>(ws, out);
}

// Round 3
// 284.235 us; speedup vs baseline: 1.0657x; 1.0021x over previous
//
#include <hip/hip_runtime.h>

#define N_THRESH 100
#define NBINS 101   // cnt in [0, 100]
#define NSUB 8      // sub-histograms per block (2 per wave, lane-parity split)

// ---------------------------------------------------------------------------
// Kernel 0: zero the workspace histogram (d_ws is poisoned 0xAA every call).
// ---------------------------------------------------------------------------
__global__ void zero_ws_kernel(unsigned long long* __restrict__ ws) {
    int i = threadIdx.x;
    if (i < NBINS) ws[i] = 0ull;
}

// ---------------------------------------------------------------------------
// Branch-free exact bin: cnt = searchsorted(thresholds, v, side='left'),
// thresholds[k] = float32(double(k)*0.01)  (bit-exact np.arange match).
// e = trunc(fl(v*100)) is within 1 of the answer (error analysis:
// |fl(v*100)-100v| <= 6e-6, |t_k - k/100| <= 6e-8), so
// cnt = e + (t_e < v) + (t_{e+1} < v) exactly. All in registers, no LDS.
// ---------------------------------------------------------------------------
__device__ __forceinline__ int bin_of(float v) {
    int e = (int)(v * 100.0f);
    e = e < 0 ? 0 : (e > 99 ? 99 : e);
    double ed = (double)e * 0.01;
    float t0 = (float)ed;           // threshold e
    float t1 = (float)(ed + 0.01);  // threshold e+1 (==1.0f when e==99: always >= v)
    int c = e + (t0 < v ? 1 : 0) + (t1 < v ? 1 : 0);
    return c > N_THRESH ? N_THRESH : c;
}

// u32-packed counters: pos in high 16 bits, total in low 16 bits.
// Overflow-safe: one sub-histogram bin receives <= 32 lanes * 64 elem = 2048
// increments per block (< 2^16), even if every element lands in one bin.
// Rationale: LDS atomics retire ~1 lane-bank-op/cycle/CU (R2 measurement);
// ds_add_u32 touches 1 bank vs 2 for u64 -> halves the bottleneck.
__device__ __forceinline__ void accum4(unsigned int* __restrict__ h,
                                       float4 p, int4 g) {
    int c0 = bin_of(p.x), c1 = bin_of(p.y), c2 = bin_of(p.z), c3 = bin_of(p.w);
    atomicAdd(&h[c0], ((unsigned int)(g.x != 0) << 16) | 1u);
    atomicAdd(&h[c1], ((unsigned int)(g.y != 0) << 16) | 1u);
    atomicAdd(&h[c2], ((unsigned int)(g.z != 0) << 16) | 1u);
    atomicAdd(&h[c3], ((unsigned int)(g.w != 0) << 16) | 1u);
}

// ---------------------------------------------------------------------------
// Kernel 1: single-pass histogram. 8 u32 LDS sub-histograms -> unpack to u64
// (pos<<32 | cnt) -> one global u64 atomic per bin per block.
// ---------------------------------------------------------------------------
__global__ __launch_bounds__(256) void hist_kernel(
        const float* __restrict__ pred,
        const int* __restrict__ gt,
        unsigned long long* __restrict__ ws,
        int n) {
    __shared__ unsigned int hist[NSUB][NBINS];

    const int tid = threadIdx.x;
    // 2 sub-histograms per wave, chosen by lane parity
    const int sub = ((tid >> 6) << 1) | (tid & 1);
    unsigned int* __restrict__ h = hist[sub];

    for (int i = tid; i < NSUB * NBINS; i += blockDim.x)
        (&hist[0][0])[i] = 0u;
    __syncthreads();

    const int nvec = n >> 2;
    const float4* __restrict__ p4 = (const float4*)pred;
    const int4*   __restrict__ g4 = (const int4*)gt;
    const int gsz = gridDim.x * blockDim.x;

    int i = blockIdx.x * blockDim.x + tid;
    // 2x unrolled: both load pairs issued before any dependent compute
    for (; i + gsz < nvec; i += 2 * gsz) {
        float4 pa = p4[i];
        int4   ga = g4[i];
        float4 pb = p4[i + gsz];
        int4   gb = g4[i + gsz];
        accum4(h, pa, ga);
        accum4(h, pb, gb);
    }
    for (; i < nvec; i += gsz) {
        accum4(h, p4[i], g4[i]);
    }

    // tail (n not multiple of 4) — empty for N=2^25
    if (blockIdx.x == 0 && tid == 0) {
        for (int k = nvec << 2; k < n; ++k) {
            int c = bin_of(pred[k]);
            atomicAdd(&hist[0][c], ((unsigned int)(gt[k] != 0) << 16) | 1u);
        }
    }

    __syncthreads();
    if (tid < NBINS) {
        unsigned long long cnt = 0ull, pos = 0ull;
#pragma unroll
        for (int w = 0; w < NSUB; ++w) {
            unsigned int v = hist[w][tid];
            cnt += v & 0xffffu;
            pos += v >> 16;
        }
        unsigned long long s = (pos << 32) | cnt;
        if (s) atomicAdd(&ws[tid], s);
    }
}

// ---------------------------------------------------------------------------
// Kernel 2: suffix sums + IoU. One block, trivial cost.
// out[0:100] = thresholds, out[100:200] = ious.
// ---------------------------------------------------------------------------
__global__ void finalize_kernel(const unsigned long long* __restrict__ ws,
                                float* __restrict__ out) {
    __shared__ unsigned int pos[NBINS], all[NBINS];
    int k = threadIdx.x;
    if (k < NBINS) {
        unsigned long long h = ws[k];
        pos[k] = (unsigned int)(h >> 32);
        all[k] = (unsigned int)(h & 0xffffffffull);
    }
    __syncthreads();
    if (k < N_THRESH) {
        out[k] = (float)((double)k * 0.01);
        unsigned long long tp = 0, pp = 0, ngt = 0;
        for (int c = k + 1; c <= N_THRESH; ++c) { tp += pos[c]; pp += all[c]; }
        for (int c = 0; c <= N_THRESH; ++c) ngt += pos[c];
        long long uni = (long long)(pp + ngt - tp);   // TP + FP + FN
        double iou = (uni > 0) ? (double)tp / (double)uni : 0.0;
        out[N_THRESH + k] = (float)iou;
    }
}

// ---------------------------------------------------------------------------
extern "C" void kernel_launch(void* const* d_in, const int* in_sizes, int n_in,
                              void* d_out, int out_size, void* d_ws, size_t ws_size,
                              hipStream_t stream) {
    const float* pred = (const float*)d_in[0];
    const int*   gt   = (const int*)d_in[1];
    float* out = (float*)d_out;
    unsigned long long* ws = (unsigned long long*)d_ws;
    int n = in_sizes[0];

    zero_ws_kernel<<<1, 128, 0, stream>>>(ws);
    // 2048 blocks x 256 threads = 8 blocks/CU on 256 CUs (fully resident)
    hist_kernel<<<2048, 256, 0, stream>>>(pred, gt, ws, n);
    finalize_kernel<<<1, 128, 0, stream>>>(ws, out);
}

// Round 4
// 281.981 us; speedup vs baseline: 1.0742x; 1.0080x over previous
//
#include <hip/hip_runtime.h>

#define N_THRESH 100
#define NBINS 101   // cnt in [0, 100]
#define COLS 32     // private columns per block (col = tid & 31)

// ---------------------------------------------------------------------------
// Kernel 0: zero the workspace histogram (d_ws is poisoned 0xAA every call).
// ---------------------------------------------------------------------------
__global__ void zero_ws_kernel(unsigned long long* __restrict__ ws) {
    int i = threadIdx.x;
    if (i < NBINS) ws[i] = 0ull;
}

// ---------------------------------------------------------------------------
// Branch-free exact bin: cnt = searchsorted(thresholds, v, side='left'),
// thresholds[k] = float32(double(k)*0.01)  (bit-exact np.arange match).
// e = trunc(fl(v*100)) is within 1 of the answer, so
// cnt = e + (t_e < v) + (t_{e+1} < v) exactly. All in registers.
// ---------------------------------------------------------------------------
__device__ __forceinline__ int bin_of(float v) {
    int e = (int)(v * 100.0f);
    e = e < 0 ? 0 : (e > 99 ? 99 : e);
    double ed = (double)e * 0.01;
    float t0 = (float)ed;           // threshold e
    float t1 = (float)(ed + 0.01);  // threshold e+1 (==1.0f when e==99)
    int c = e + (t0 < v ? 1 : 0) + (t1 < v ? 1 : 0);
    return c > N_THRESH ? N_THRESH : c;
}

// ---------------------------------------------------------------------------
// Kernel 1: single-pass histogram.
// hist[bin][col]: col = tid&31 -> per-lane-pair private columns:
//   - no same-address atomics within a wave except same-bin (L, L+32) pairs
//     (p ~ 1/101, negligible serialization)
//   - bank = col mod 32 for ANY bin -> fixed 2 lanes/bank = conflict-free
// u32 packing [gt:16 | cnt:16]: per-cell max = 8 threads * 64 elem = 512,
// exact. 8x unrolled loads: 16 x 16B outstanding per wave (load concurrency).
// ---------------------------------------------------------------------------
__global__ __launch_bounds__(256) void hist_kernel(
        const float* __restrict__ pred,
        const int* __restrict__ gt,
        unsigned long long* __restrict__ ws,
        int n) {
    __shared__ unsigned int hist[NBINS][COLS];   // 12.9 KB

    const int tid = threadIdx.x;
    const int col = tid & (COLS - 1);

    for (int i = tid; i < NBINS * COLS; i += 256)
        (&hist[0][0])[i] = 0u;
    __syncthreads();

    const int nvec = n >> 2;
    const float4* __restrict__ p4 = (const float4*)pred;
    const int4*   __restrict__ g4 = (const int4*)gt;
    const int gsz = gridDim.x * blockDim.x;

    int i = blockIdx.x * blockDim.x + tid;
    // 8x unrolled: all 16 loads issued before any dependent compute
    for (; i + 7 * gsz < nvec; i += 8 * gsz) {
        float4 p[8];
        int4   g[8];
#pragma unroll
        for (int u = 0; u < 8; ++u) {
            p[u] = p4[i + u * gsz];
            g[u] = g4[i + u * gsz];
        }
#pragma unroll
        for (int u = 0; u < 8; ++u) {
            atomicAdd(&hist[bin_of(p[u].x)][col],
                      1u | ((unsigned int)(g[u].x != 0) << 16));
            atomicAdd(&hist[bin_of(p[u].y)][col],
                      1u | ((unsigned int)(g[u].y != 0) << 16));
            atomicAdd(&hist[bin_of(p[u].z)][col],
                      1u | ((unsigned int)(g[u].z != 0) << 16));
            atomicAdd(&hist[bin_of(p[u].w)][col],
                      1u | ((unsigned int)(g[u].w != 0) << 16));
        }
    }
    for (; i < nvec; i += gsz) {
        float4 p = p4[i];
        int4   g = g4[i];
        atomicAdd(&hist[bin_of(p.x)][col], 1u | ((unsigned int)(g.x != 0) << 16));
        atomicAdd(&hist[bin_of(p.y)][col], 1u | ((unsigned int)(g.y != 0) << 16));
        atomicAdd(&hist[bin_of(p.z)][col], 1u | ((unsigned int)(g.z != 0) << 16));
        atomicAdd(&hist[bin_of(p.w)][col], 1u | ((unsigned int)(g.w != 0) << 16));
    }

    // tail (n not multiple of 4) — empty for N=2^25
    if (blockIdx.x == 0 && tid == 0) {
        for (int k = nvec << 2; k < n; ++k) {
            atomicAdd(&hist[bin_of(pred[k])][0],
                      1u | ((unsigned int)(gt[k] != 0) << 16));
        }
    }

    __syncthreads();
    if (tid < NBINS) {
        unsigned long long cnt = 0ull, pos = 0ull;
#pragma unroll
        for (int j = 0; j < COLS; ++j) {
            // staggered column order -> conflict-free fold reads
            unsigned int v = hist[tid][(j + tid) & (COLS - 1)];
            cnt += v & 0xffffu;
            pos += v >> 16;
        }
        unsigned long long s = (pos << 32) | cnt;
        if (s) atomicAdd(&ws[tid], s);
    }
}

// ---------------------------------------------------------------------------
// Kernel 2: suffix sums + IoU. One block, trivial cost.
// out[0:100] = thresholds, out[100:200] = ious.
// ---------------------------------------------------------------------------
__global__ void finalize_kernel(const unsigned long long* __restrict__ ws,
                                float* __restrict__ out) {
    __shared__ unsigned int pos[NBINS], all[NBINS];
    int k = threadIdx.x;
    if (k < NBINS) {
        unsigned long long h = ws[k];
        pos[k] = (unsigned int)(h >> 32);
        all[k] = (unsigned int)(h & 0xffffffffull);
    }
    __syncthreads();
    if (k < N_THRESH) {
        out[k] = (float)((double)k * 0.01);
        unsigned long long tp = 0, pp = 0, ngt = 0;
        for (int c = k + 1; c <= N_THRESH; ++c) { tp += pos[c]; pp += all[c]; }
        for (int c = 0; c <= N_THRESH; ++c) ngt += pos[c];
        long long uni = (long long)(pp + ngt - tp);   // TP + FP + FN
        double iou = (uni > 0) ? (double)tp / (double)uni : 0.0;
        out[N_THRESH + k] = (float)iou;
    }
}

// ---------------------------------------------------------------------------
extern "C" void kernel_launch(void* const* d_in, const int* in_sizes, int n_in,
                              void* d_out, int out_size, void* d_ws, size_t ws_size,
                              hipStream_t stream) {
    const float* pred = (const float*)d_in[0];
    const int*   gt   = (const int*)d_in[1];
    float* out = (float*)d_out;
    unsigned long long* ws = (unsigned long long*)d_ws;
    int n = in_sizes[0];

    zero_ws_kernel<<<1, 128, 0, stream>>>(ws);
    // 2048 blocks x 256 threads = 8 blocks/CU on 256 CUs (fully resident);
    // N/threads = exactly 16 float4 per thread -> two clean 8x iterations
    hist_kernel<<<2048, 256, 0, stream>>>(pred, gt, ws, n);
    finalize_kernel<<<1, 128, 0, stream>>>(ws, out);
}